// Round 3
// baseline (15598.373 us; speedup 1.0000x reference)
//
#include <hip/hip_runtime.h>
#include <hip/hip_bf16.h>
#include <math.h>

#define B 32
#define NN 4096
#define DK 128
#define HH 128
#define AA 128

// ws layout (in floats)
static const size_t OFF_ZF   = 0;                       // B*NN*AA = 16777216
static const size_t OFF_P    = OFF_ZF + (size_t)B*NN*AA; // B*NN
static const size_t OFF_COV  = OFF_P + (size_t)B*NN;     // B*NN
static const size_t OFF_S    = OFF_COV + (size_t)B*NN;   // 2*B
static const size_t OFF_CTX  = OFF_S + 2*B;              // 2*B*DK
static const size_t OFF_DECQ = OFF_CTX + (size_t)2*B*DK; // B*AA
static const size_t OFF_HST  = OFF_DECQ + (size_t)B*AA;  // B*HH
static const size_t OFF_CST  = OFF_HST + (size_t)B*HH;   // B*HH
static const size_t OFF_CNT  = OFF_CST + (size_t)B*HH;   // B ints

__device__ __forceinline__ float fast_tanh(float x) {
    float e = __expf(2.f * x);
    return 1.f - 2.f / (e + 1.f);
}
__device__ __forceinline__ float fast_sig(float x) {
    return 1.f / (1.f + __expf(-x));
}
__device__ __forceinline__ float agent_load(const float* p) {
    return __hip_atomic_load(p, __ATOMIC_RELAXED, __HIP_MEMORY_SCOPE_AGENT);
}

// ---- LSTM + dec_fea ("phase A") ----------------------------------------
// Requires >=256 threads; all threads of the block must call.
__device__ void lstm_phase(int tid, int b, const float* __restrict__ sm_s,
                           float* hst, float* cst, float* decq,
                           const float* __restrict__ W_ih, const float* __restrict__ W_hh,
                           const float* __restrict__ b_ih, const float* __restrict__ b_hh,
                           const float* __restrict__ W_x, const float* __restrict__ b_attn)
{
    __shared__ float sm_h[HH];
    __shared__ float sm_g[4 * HH];
    __shared__ float sm_x[2 * HH];
    if (tid < HH) sm_h[tid] = hst[b * HH + tid];
    __syncthreads();
    if (tid < 256) {
        int j0 = tid, j1 = tid + 256;
        float g0 = b_ih[j0] + b_hh[j0];
        float g1 = b_ih[j1] + b_hh[j1];
        const float4* wi0 = (const float4*)(W_ih + (size_t)j0 * DK);
        const float4* wh0 = (const float4*)(W_hh + (size_t)j0 * HH);
        const float4* wi1 = (const float4*)(W_ih + (size_t)j1 * DK);
        const float4* wh1 = (const float4*)(W_hh + (size_t)j1 * HH);
        #pragma unroll 8
        for (int d4 = 0; d4 < DK / 4; ++d4) {
            float4 s4 = ((const float4*)sm_s)[d4];
            float4 h4 = ((const float4*)sm_h)[d4];
            float4 a0 = wi0[d4], a1 = wi1[d4];
            float4 c0 = wh0[d4], c1 = wh1[d4];
            g0 += s4.x*a0.x + s4.y*a0.y + s4.z*a0.z + s4.w*a0.w
                + h4.x*c0.x + h4.y*c0.y + h4.z*c0.z + h4.w*c0.w;
            g1 += s4.x*a1.x + s4.y*a1.y + s4.z*a1.z + s4.w*a1.w
                + h4.x*c1.x + h4.y*c1.y + h4.z*c1.z + h4.w*c1.w;
        }
        sm_g[j0] = g0; sm_g[j1] = g1;
    }
    __syncthreads();
    if (tid < HH) {
        float ig = sm_g[tid], fg = sm_g[HH + tid];
        float gg = sm_g[2 * HH + tid], og = sm_g[3 * HH + tid];
        float cold = cst[b * HH + tid];
        float cn = fast_sig(fg) * cold + fast_sig(ig) * fast_tanh(gg);
        float hn = fast_sig(og) * fast_tanh(cn);
        cst[b * HH + tid] = cn;
        hst[b * HH + tid] = hn;
        sm_x[tid] = hn;
        sm_x[HH + tid] = cn;
    }
    __syncthreads();
    if (tid < AA) {
        float df = b_attn[tid];
        #pragma unroll 8
        for (int k4 = 0; k4 < (2 * HH) / 4; ++k4) {
            float4 xv = ((const float4*)sm_x)[k4];
            df += xv.x * W_x[(size_t)(4 * k4 + 0) * AA + tid]
                + xv.y * W_x[(size_t)(4 * k4 + 1) * AA + tid]
                + xv.z * W_x[(size_t)(4 * k4 + 2) * AA + tid]
                + xv.w * W_x[(size_t)(4 * k4 + 3) * AA + tid];
        }
        decq[b * AA + tid] = df;
    }
    __syncthreads();
}

// ---- z_fea = z @ W_z ----------------------------------------------------
__global__ __launch_bounds__(256) void zfea_kernel(const float* __restrict__ z,
                                                   const float* __restrict__ Wz,
                                                   float* __restrict__ zf)
{
    __shared__ float sz[64 * DK];  // 32 KB
    const int tid = threadIdx.x;
    const size_t r0 = (size_t)blockIdx.x * 64;
    const float4* zsrc = (const float4*)(z + r0 * DK);
    float4* sz4 = (float4*)sz;
    #pragma unroll
    for (int i = 0; i < 8; ++i) sz4[i * 256 + tid] = zsrc[i * 256 + tid];
    __syncthreads();

    const int a4 = tid & 31;   // cols 4*a4 .. 4*a4+3
    const int g  = tid >> 5;   // rows g*8 .. g*8+7
    float4 acc[8];
    #pragma unroll
    for (int r = 0; r < 8; ++r) acc[r] = make_float4(0.f, 0.f, 0.f, 0.f);
    const float4* Wz4 = (const float4*)Wz;  // [128 d][32 col-quads]
    for (int d4 = 0; d4 < 32; ++d4) {
        float4 w0 = Wz4[(4 * d4 + 0) * 32 + a4];
        float4 w1 = Wz4[(4 * d4 + 1) * 32 + a4];
        float4 w2 = Wz4[(4 * d4 + 2) * 32 + a4];
        float4 w3 = Wz4[(4 * d4 + 3) * 32 + a4];
        #pragma unroll
        for (int r = 0; r < 8; ++r) {
            float4 zv = *(const float4*)(&sz[(g * 8 + r) * DK + 4 * d4]);
            acc[r].x += zv.x * w0.x + zv.y * w1.x + zv.z * w2.x + zv.w * w3.x;
            acc[r].y += zv.x * w0.y + zv.y * w1.y + zv.z * w2.y + zv.w * w3.y;
            acc[r].z += zv.x * w0.z + zv.y * w1.z + zv.z * w2.z + zv.w * w3.z;
            acc[r].w += zv.x * w0.w + zv.y * w1.w + zv.z * w2.w + zv.w * w3.w;
        }
    }
    #pragma unroll
    for (int r = 0; r < 8; ++r)
        *(float4*)(&zf[(r0 + g * 8 + r) * AA + 4 * a4]) = acc[r];
}

// ---- prologue: zero state + initial LSTM (s=0, h0, c0) ------------------
__global__ __launch_bounds__(256) void prologue_kernel(
    const float* __restrict__ h0, const float* __restrict__ c0,
    float* cov, float* S, float* ctx, float* decq, float* hst, float* cst,
    int* cnt, float* out_closs,
    const float* __restrict__ W_ih, const float* __restrict__ W_hh,
    const float* __restrict__ b_ih, const float* __restrict__ b_hh,
    const float* __restrict__ W_x, const float* __restrict__ b_attn)
{
    int b = blockIdx.x;
    int tid = threadIdx.x;
    float4 zero4 = make_float4(0.f, 0.f, 0.f, 0.f);
    float4* c4 = (float4*)(cov + (size_t)b * NN);
    for (int i = tid; i < NN / 4; i += 256) c4[i] = zero4;
    if (tid < DK) ctx[b * DK + tid] = 0.f;  // ctx[buf 0]
    if (tid == 0) {
        S[b] = 0.f;
        cnt[b] = 0;
        if (b == 0) *out_closs = 0.f;
    }
    if (tid < HH) {
        hst[b * HH + tid] = h0[b * HH + tid];
        cst[b * HH + tid] = c0[b * HH + tid];
    }
    __shared__ float sm_s[DK];
    if (tid < DK) sm_s[tid] = 0.f;
    __syncthreads();
    lstm_phase(tid, b, sm_s, hst, cst, decq, W_ih, W_hh, b_ih, b_hh, W_x, b_attn);
}

// ---- one decode step ----------------------------------------------------
// v3: grid 2048 = 32 b * 64 chunks of 64 n; block 256 threads (4 waves,
// 16 n/wave in 2 groups of 8). VGPR<=64 -> 8 waves/SIMD; 8 blocks/CU ->
// 32 waves/CU resident for latency hiding.
__global__ __launch_bounds__(256) void step_kernel(
    const float* __restrict__ z, const float* __restrict__ mask,
    const float* __restrict__ w_c, const float* __restrict__ v,
    const float* __restrict__ zf, float* __restrict__ p, float* __restrict__ cov,
    float* S, float* ctx, float* decq, float* hst, float* cst, int* cnt,
    const float* __restrict__ W_ih, const float* __restrict__ W_hh,
    const float* __restrict__ b_ih, const float* __restrict__ b_hh,
    const float* __restrict__ W_x, const float* __restrict__ b_attn,
    float* __restrict__ out_text, float* __restrict__ out_attn, float* out_closs,
    int t, int T)
{
    const int tid = threadIdx.x;
    const int b = blockIdx.x & (B - 1);
    const int chunk = blockIdx.x >> 5;
    const int n0 = chunk * 64;
    const int cur = t & 1, prv = cur ^ 1;

    __shared__ float sm_cov[64];
    __shared__ float sm_p[64];
    __shared__ float sm_ctx[4][DK];
    __shared__ float sm_sump[4];
    __shared__ float sm_red[4];
    __shared__ int sm_done;

    float closs_part = 0.f;
    // --- B.1: finalize previous step's attention lazily (coalesced per n) ---
    if (tid < 64) {
        int n = n0 + tid;
        size_t bn = (size_t)b * NN + n;
        float covn = cov[bn];
        if (t > 0) {
            float invS = 1.f / S[prv * B + b];
            float ap = p[bn] * invS;
            __builtin_nontemporal_store(ap, &out_attn[((size_t)b * T + (t - 1)) * NN + n]);
            closs_part = fminf(ap, covn);
            covn += ap;
            cov[bn] = covn;
        }
        sm_cov[tid] = covn;
    }
    __syncthreads();

    // --- B.2: scores + exp + unnormalized context, 8 n per wave-iteration ---
    const int w = tid >> 6, l = tid & 63;
    const float2* zf2 = (const float2*)(zf + ((size_t)b * NN + n0) * AA);
    const float2* z2  = (const float2*)(z  + ((size_t)b * NN + n0) * DK);
    const float2 q   = ((const float2*)(decq + b * AA))[l];   // dec_fea + b_attn
    const float2 wc2 = ((const float2*)w_c)[l];
    const float2 v2  = ((const float2*)v)[l];
    const float* mrow = mask + (size_t)b * NN + n0;
    float accx = 0.f, accy = 0.f;
    float sump = 0.f;
    #pragma unroll 1
    for (int i0 = 0; i0 < 16; i0 += 8) {
        const int nb = w * 16 + i0;
        float2 a2[8], zr[8];
        #pragma unroll
        for (int g = 0; g < 8; ++g) a2[g] = zf2[(size_t)(nb + g) * 64 + l];
        #pragma unroll
        for (int g = 0; g < 8; ++g) zr[g] = z2[(size_t)(nb + g) * 64 + l];
        float el[8];
        #pragma unroll
        for (int g = 0; g < 8; ++g) {
            float cvn = sm_cov[nb + g];
            float x0 = fmaf(cvn, wc2.x, a2[g].x + q.x);
            float x1 = fmaf(cvn, wc2.y, a2[g].y + q.y);
            el[g] = fast_tanh(x0) * v2.x + fast_tanh(x1) * v2.y;
        }
        #pragma unroll
        for (int off = 32; off; off >>= 1) {
            #pragma unroll
            for (int g = 0; g < 8; ++g) el[g] += __shfl_xor(el[g], off, 64);
        }
        #pragma unroll
        for (int g = 0; g < 8; ++g) {
            float pe = (mrow[nb + g] > 0.f) ? __expf(el[g]) : 0.f;
            if (l == 0) sm_p[nb + g] = pe;
            accx = fmaf(pe, zr[g].x, accx);
            accy = fmaf(pe, zr[g].y, accy);
            sump += pe;
        }
    }
    sm_ctx[w][2 * l]     = accx;
    sm_ctx[w][2 * l + 1] = accy;
    if (l == 0) sm_sump[w] = sump;
    #pragma unroll
    for (int off = 32; off; off >>= 1) closs_part += __shfl_xor(closs_part, off, 64);
    if (l == 0) sm_red[w] = closs_part;
    __syncthreads();

    // --- B.3: coalesced p store + block-level reduction into globals ---
    if (tid < 64) p[(size_t)b * NN + n0 + tid] = sm_p[tid];
    if (tid < DK) {
        float r = 0.f;
        #pragma unroll
        for (int ww = 0; ww < 4; ++ww) r += sm_ctx[ww][tid];
        atomicAdd(&ctx[(cur * B + b) * DK + tid], r);
    } else if (tid == DK) {
        float s4 = 0.f;
        #pragma unroll
        for (int ww = 0; ww < 4; ++ww) s4 += sm_sump[ww];
        atomicAdd(&S[cur * B + b], s4);
    } else if (tid == DK + 1 && t > 0) {
        float cl = 0.f;
        #pragma unroll
        for (int ww = 0; ww < 4; ++ww) cl += sm_red[ww];
        atomicAdd(out_closs, cl * (1.f / B));
    }
    __threadfence();
    __syncthreads();
    if (tid == 0) {
        int old = __hip_atomic_fetch_add(&cnt[b], 1, __ATOMIC_ACQ_REL, __HIP_MEMORY_SCOPE_AGENT);
        sm_done = (old == 63) ? 1 : 0;
    }
    __syncthreads();

    // --- last block for this b: normalize context, write text, next LSTM ---
    if (sm_done) {
        __shared__ float sm_s[DK];
        if (tid < DK) {
            float Sv = agent_load(&S[cur * B + b]);
            float cval = agent_load(&ctx[(cur * B + b) * DK + tid]);
            float ct = cval / Sv;
            __builtin_nontemporal_store(ct, &out_text[((size_t)b * T + t) * DK + tid]);
            sm_s[tid] = ct;
            ctx[(prv * B + b) * DK + tid] = 0.f;  // accumulator for step t+1
        }
        if (tid == 0) {
            S[prv * B + b] = 0.f;
            __hip_atomic_store(&cnt[b], 0, __ATOMIC_RELAXED, __HIP_MEMORY_SCOPE_AGENT);
        }
        __syncthreads();
        lstm_phase(tid, b, sm_s, hst, cst, decq, W_ih, W_hh, b_ih, b_hh, W_x, b_attn);
    }
}

// ---- epilogue: last step's attention + closs term -----------------------
__global__ __launch_bounds__(256) void epilogue_kernel(
    const float* __restrict__ p, const float* __restrict__ cov, const float* __restrict__ S,
    float* __restrict__ out_attn, float* out_closs, int T)
{
    const int tid = threadIdx.x;
    const int b = blockIdx.x & (B - 1);
    const int chunk = blockIdx.x >> 5;
    const int n = chunk * 256 + tid;
    const size_t bn = (size_t)b * NN + n;
    float invS = 1.f / S[((T - 1) & 1) * B + b];
    float ap = p[bn] * invS;
    __builtin_nontemporal_store(ap, &out_attn[((size_t)b * T + (T - 1)) * NN + n]);
    float cl = fminf(ap, cov[bn]);
    #pragma unroll
    for (int off = 32; off; off >>= 1) cl += __shfl_xor(cl, off, 64);
    __shared__ float sred[4];
    if ((tid & 63) == 0) sred[tid >> 6] = cl;
    __syncthreads();
    if (tid == 0)
        atomicAdd(out_closs, (sred[0] + sred[1] + sred[2] + sred[3]) * (1.f / B));
}

extern "C" void kernel_launch(void* const* d_in, const int* in_sizes, int n_in,
                              void* d_out, int out_size, void* d_ws, size_t ws_size,
                              hipStream_t stream) {
    const float* z      = (const float*)d_in[0];
    const float* mask   = (const float*)d_in[1];
    const float* h0     = (const float*)d_in[2];
    const float* c0     = (const float*)d_in[3];
    const float* W_ih   = (const float*)d_in[4];
    const float* W_hh   = (const float*)d_in[5];
    const float* b_ih   = (const float*)d_in[6];
    const float* b_hh   = (const float*)d_in[7];
    const float* W_x    = (const float*)d_in[8];
    const float* W_z    = (const float*)d_in[9];
    const float* w_c    = (const float*)d_in[10];
    const float* b_attn = (const float*)d_in[11];
    const float* v      = (const float*)d_in[12];

    int T = (out_size - 1) / (B * (NN + DK));
    if (T < 1) T = 1;

    float* ws   = (float*)d_ws;
    float* zf   = ws + OFF_ZF;
    float* p    = ws + OFF_P;
    float* cov  = ws + OFF_COV;
    float* S    = ws + OFF_S;
    float* ctx  = ws + OFF_CTX;
    float* decq = ws + OFF_DECQ;
    float* hst  = ws + OFF_HST;
    float* cst  = ws + OFF_CST;
    int*   cnt  = (int*)(ws + OFF_CNT);

    float* out_text  = (float*)d_out;
    float* out_attn  = out_text + (size_t)B * T * DK;
    float* out_closs = out_attn + (size_t)B * T * NN;

    zfea_kernel<<<(B * NN) / 64, 256, 0, stream>>>(z, W_z, zf);
    prologue_kernel<<<B, 256, 0, stream>>>(h0, c0, cov, S, ctx, decq, hst, cst,
                                           cnt, out_closs,
                                           W_ih, W_hh, b_ih, b_hh, W_x, b_attn);
    for (int t = 0; t < T; ++t) {
        step_kernel<<<2048, 256, 0, stream>>>(z, mask, w_c, v, zf, p, cov, S, ctx,
                                              decq, hst, cst, cnt,
                                              W_ih, W_hh, b_ih, b_hh, W_x, b_attn,
                                              out_text, out_attn, out_closs, t, T);
    }
    epilogue_kernel<<<512, 256, 0, stream>>>(p, cov, S, out_attn, out_closs, T);
}

// Round 4
// 5227.143 us; speedup vs baseline: 2.9841x; 2.9841x over previous
//
#include <hip/hip_runtime.h>
#include <hip/hip_bf16.h>
#include <math.h>

#define B 32
#define NN 4096
#define DK 128
#define HH 128
#define AA 128
#define NCH 32        // chunks per batch row
#define CHN 128       // n per chunk

// ws layout (in floats)
static const size_t OFF_ZF   = 0;                         // B*NN*AA
static const size_t OFF_P    = OFF_ZF + (size_t)B*NN*AA;  // B*NN
static const size_t OFF_COV  = OFF_P + (size_t)B*NN;      // B*NN
static const size_t OFF_SRED = OFF_COV + (size_t)B*NN;    // 2*B
static const size_t OFF_PCTX = OFF_SRED + 2*B;            // B*NCH*DK
static const size_t OFF_PSUM = OFF_PCTX + (size_t)B*NCH*DK; // B*NCH
static const size_t OFF_PCL  = OFF_PSUM + (size_t)B*NCH;  // B*NCH
static const size_t OFF_DECQ = OFF_PCL + (size_t)B*NCH;   // B*AA
static const size_t OFF_HST  = OFF_DECQ + (size_t)B*AA;   // B*HH
static const size_t OFF_CST  = OFF_HST + (size_t)B*HH;    // B*HH
static const size_t OFF_CNT  = OFF_CST + (size_t)B*HH;    // B ints

__device__ __forceinline__ float fast_tanh(float x) {
    float e = __expf(2.f * x);
    return 1.f - 2.f / (e + 1.f);
}
__device__ __forceinline__ float fast_sig(float x) {
    return 1.f / (1.f + __expf(-x));
}
__device__ __forceinline__ float agent_load(const float* p) {
    return __hip_atomic_load(p, __ATOMIC_RELAXED, __HIP_MEMORY_SCOPE_AGENT);
}

// ---- LSTM + dec_fea ----------------------------------------------------
// Workers are tid<256; every thread of the block must call (has barriers).
__device__ void lstm_phase(int tid, int b, const float* __restrict__ sm_s,
                           float* hst, float* cst, float* decq,
                           const float* __restrict__ W_ih, const float* __restrict__ W_hh,
                           const float* __restrict__ b_ih, const float* __restrict__ b_hh,
                           const float* __restrict__ W_x, const float* __restrict__ b_attn)
{
    __shared__ float sm_h[HH];
    __shared__ float sm_g[4 * HH];
    __shared__ float sm_x[2 * HH];
    if (tid < HH) sm_h[tid] = hst[b * HH + tid];
    __syncthreads();
    if (tid < 256) {
        int j0 = tid, j1 = tid + 256;
        float g0 = b_ih[j0] + b_hh[j0];
        float g1 = b_ih[j1] + b_hh[j1];
        const float4* wi0 = (const float4*)(W_ih + (size_t)j0 * DK);
        const float4* wh0 = (const float4*)(W_hh + (size_t)j0 * HH);
        const float4* wi1 = (const float4*)(W_ih + (size_t)j1 * DK);
        const float4* wh1 = (const float4*)(W_hh + (size_t)j1 * HH);
        #pragma unroll 8
        for (int d4 = 0; d4 < DK / 4; ++d4) {
            float4 s4 = ((const float4*)sm_s)[d4];
            float4 h4 = ((const float4*)sm_h)[d4];
            float4 a0 = wi0[d4], a1 = wi1[d4];
            float4 c0 = wh0[d4], c1 = wh1[d4];
            g0 += s4.x*a0.x + s4.y*a0.y + s4.z*a0.z + s4.w*a0.w
                + h4.x*c0.x + h4.y*c0.y + h4.z*c0.z + h4.w*c0.w;
            g1 += s4.x*a1.x + s4.y*a1.y + s4.z*a1.z + s4.w*a1.w
                + h4.x*c1.x + h4.y*c1.y + h4.z*c1.z + h4.w*c1.w;
        }
        sm_g[j0] = g0; sm_g[j1] = g1;
    }
    __syncthreads();
    if (tid < HH) {
        float ig = sm_g[tid], fg = sm_g[HH + tid];
        float gg = sm_g[2 * HH + tid], og = sm_g[3 * HH + tid];
        float cold = cst[b * HH + tid];
        float cn = fast_sig(fg) * cold + fast_sig(ig) * fast_tanh(gg);
        float hn = fast_sig(og) * fast_tanh(cn);
        cst[b * HH + tid] = cn;
        hst[b * HH + tid] = hn;
        sm_x[tid] = hn;
        sm_x[HH + tid] = cn;
    }
    __syncthreads();
    if (tid < AA) {
        float df = b_attn[tid];
        #pragma unroll 8
        for (int k4 = 0; k4 < (2 * HH) / 4; ++k4) {
            float4 xv = ((const float4*)sm_x)[k4];
            df += xv.x * W_x[(size_t)(4 * k4 + 0) * AA + tid]
                + xv.y * W_x[(size_t)(4 * k4 + 1) * AA + tid]
                + xv.z * W_x[(size_t)(4 * k4 + 2) * AA + tid]
                + xv.w * W_x[(size_t)(4 * k4 + 3) * AA + tid];
        }
        decq[b * AA + tid] = df;
    }
    __syncthreads();
}

// ---- z_fea = z @ W_z ----------------------------------------------------
// 32 rows/block in LDS (16 KB); Wz coalesced from global (L2-hot).
__global__ __launch_bounds__(256) void zfea_kernel(const float* __restrict__ z,
                                                   const float* __restrict__ Wz,
                                                   float* __restrict__ zf)
{
    __shared__ float sz[32 * DK];  // 16 KB
    const int tid = threadIdx.x;
    const size_t r0 = (size_t)blockIdx.x * 32;
    const float4* zsrc = (const float4*)(z + r0 * DK);
    float4* sz4 = (float4*)sz;
    #pragma unroll
    for (int i = 0; i < 4; ++i) sz4[i * 256 + tid] = zsrc[i * 256 + tid];
    __syncthreads();

    const int a4 = tid & 31;   // cols 4*a4 .. 4*a4+3
    const int g  = tid >> 5;   // rows g*4 .. g*4+3
    float4 acc[4];
    #pragma unroll
    for (int r = 0; r < 4; ++r) acc[r] = make_float4(0.f, 0.f, 0.f, 0.f);
    const float4* Wz4 = (const float4*)Wz;  // [128 d][32 col-quads]
    for (int d4 = 0; d4 < 32; ++d4) {
        float4 w0 = Wz4[(4 * d4 + 0) * 32 + a4];
        float4 w1 = Wz4[(4 * d4 + 1) * 32 + a4];
        float4 w2 = Wz4[(4 * d4 + 2) * 32 + a4];
        float4 w3 = Wz4[(4 * d4 + 3) * 32 + a4];
        #pragma unroll
        for (int r = 0; r < 4; ++r) {
            float4 zv = *(const float4*)(&sz[(g * 4 + r) * DK + 4 * d4]);
            acc[r].x += zv.x * w0.x + zv.y * w1.x + zv.z * w2.x + zv.w * w3.x;
            acc[r].y += zv.x * w0.y + zv.y * w1.y + zv.z * w2.y + zv.w * w3.y;
            acc[r].z += zv.x * w0.z + zv.y * w1.z + zv.z * w2.z + zv.w * w3.z;
            acc[r].w += zv.x * w0.w + zv.y * w1.w + zv.z * w2.w + zv.w * w3.w;
        }
    }
    #pragma unroll
    for (int r = 0; r < 4; ++r)
        *(float4*)(&zf[(r0 + g * 4 + r) * AA + 4 * a4]) = acc[r];
}

// ---- prologue ------------------------------------------------------------
__global__ __launch_bounds__(256) void prologue_kernel(
    const float* __restrict__ h0, const float* __restrict__ c0,
    float* cov, float* decq, float* hst, float* cst,
    int* cnt, float* out_closs,
    const float* __restrict__ W_ih, const float* __restrict__ W_hh,
    const float* __restrict__ b_ih, const float* __restrict__ b_hh,
    const float* __restrict__ W_x, const float* __restrict__ b_attn)
{
    int b = blockIdx.x;
    int tid = threadIdx.x;
    float4 zero4 = make_float4(0.f, 0.f, 0.f, 0.f);
    float4* c4 = (float4*)(cov + (size_t)b * NN);
    for (int i = tid; i < NN / 4; i += 256) c4[i] = zero4;
    if (tid == 0) {
        cnt[b] = 0;
        if (b == 0) *out_closs = 0.f;
    }
    if (tid < HH) {
        hst[b * HH + tid] = h0[b * HH + tid];
        cst[b * HH + tid] = c0[b * HH + tid];
    }
    __shared__ float sm_s[DK];
    if (tid < DK) sm_s[tid] = 0.f;
    __syncthreads();
    lstm_phase(tid, b, sm_s, hst, cst, decq, W_ih, W_hh, b_ih, b_hh, W_x, b_attn);
}

// ---- one decode step -----------------------------------------------------
// grid 1024 = 32 b * 32 chunks of 128 n; block 512 (8 waves, 16 n/wave).
// No contended atomics: per-chunk partials in ws + one ACQ_REL ticket/block.
__global__ __launch_bounds__(512, 8) void step_kernel(
    const float* __restrict__ z, const float* __restrict__ mask,
    const float* __restrict__ w_c, const float* __restrict__ v,
    const float* __restrict__ zf, float* __restrict__ p, float* __restrict__ cov,
    float* Sred, float* pctx, float* psum, float* pcl,
    float* decq, float* hst, float* cst, int* cnt,
    const float* __restrict__ W_ih, const float* __restrict__ W_hh,
    const float* __restrict__ b_ih, const float* __restrict__ b_hh,
    const float* __restrict__ W_x, const float* __restrict__ b_attn,
    float* __restrict__ out_text, float* __restrict__ out_attn, float* out_closs,
    int t, int T)
{
    const int tid = threadIdx.x;
    const int b = blockIdx.x & (B - 1);
    const int chunk = blockIdx.x >> 5;
    const int n0 = chunk * CHN;
    const int cur = t & 1, prv = cur ^ 1;

    __shared__ float sm_cov[CHN];
    __shared__ float sm_mask[CHN];
    __shared__ float sm_p[CHN];
    __shared__ float sm_ctx[8][DK];
    __shared__ float sm_sump[8];
    __shared__ float sm_red[2];
    __shared__ int sm_done;

    // --- B.1: finalize previous step's attention lazily; stage mask ---
    if (tid < CHN) {
        int n = n0 + tid;
        size_t bn = (size_t)b * NN + n;
        float covn = cov[bn];
        float closs_part = 0.f;
        if (t > 0) {
            float invS = 1.f / Sred[prv * B + b];
            float ap = p[bn] * invS;
            __builtin_nontemporal_store(ap, &out_attn[((size_t)b * T + (t - 1)) * NN + n]);
            closs_part = fminf(ap, covn);
            covn += ap;
            cov[bn] = covn;
        }
        sm_cov[tid] = covn;
        #pragma unroll
        for (int off = 32; off; off >>= 1) closs_part += __shfl_xor(closs_part, off, 64);
        if ((tid & 63) == 0) sm_red[tid >> 6] = closs_part;
    } else if (tid < 2 * CHN) {
        sm_mask[tid - CHN] = mask[(size_t)b * NN + n0 + (tid - CHN)];
    }
    __syncthreads();

    // --- B.2: scores + exp + unnormalized context, 8 n per wave-iteration ---
    const int w = tid >> 6, l = tid & 63;
    const float2* zf2 = (const float2*)(zf + ((size_t)b * NN + n0) * AA);
    const float2* z2  = (const float2*)(z  + ((size_t)b * NN + n0) * DK);
    const float2 q   = ((const float2*)(decq + b * AA))[l];   // dec_fea + b_attn
    const float2 wc2 = ((const float2*)w_c)[l];
    const float2 v2  = ((const float2*)v)[l];
    float accx = 0.f, accy = 0.f;
    float sump = 0.f;
    #pragma unroll 1
    for (int i0 = 0; i0 < 16; i0 += 8) {
        const int nb = w * 16 + i0;
        float2 a2[8], zr[8];
        #pragma unroll
        for (int g = 0; g < 8; ++g) a2[g] = zf2[(size_t)(nb + g) * 64 + l];
        #pragma unroll
        for (int g = 0; g < 8; ++g) zr[g] = z2[(size_t)(nb + g) * 64 + l];
        float el[8];
        #pragma unroll
        for (int g = 0; g < 8; ++g) {
            float cvn = sm_cov[nb + g];
            float x0 = fmaf(cvn, wc2.x, a2[g].x + q.x);
            float x1 = fmaf(cvn, wc2.y, a2[g].y + q.y);
            el[g] = fast_tanh(x0) * v2.x + fast_tanh(x1) * v2.y;
        }
        #pragma unroll
        for (int off = 32; off; off >>= 1) {
            #pragma unroll
            for (int g = 0; g < 8; ++g) el[g] += __shfl_xor(el[g], off, 64);
        }
        #pragma unroll
        for (int g = 0; g < 8; ++g) {
            float pe = (sm_mask[nb + g] > 0.f) ? __expf(el[g]) : 0.f;
            if (l == 0) sm_p[nb + g] = pe;
            accx = fmaf(pe, zr[g].x, accx);
            accy = fmaf(pe, zr[g].y, accy);
            sump += pe;
        }
    }
    sm_ctx[w][2 * l]     = accx;
    sm_ctx[w][2 * l + 1] = accy;
    if (l == 0) sm_sump[w] = sump;
    __syncthreads();

    // --- B.3: private partial stores (no contended atomics) ---
    if (tid < CHN) p[(size_t)b * NN + n0 + tid] = sm_p[tid];
    if (tid < DK) {
        float r = 0.f;
        #pragma unroll
        for (int ww = 0; ww < 8; ++ww) r += sm_ctx[ww][tid];
        pctx[((size_t)b * NCH + chunk) * DK + tid] = r;
    } else if (tid == DK) {
        float s8 = 0.f;
        #pragma unroll
        for (int ww = 0; ww < 8; ++ww) s8 += sm_sump[ww];
        psum[b * NCH + chunk] = s8;
    } else if (tid == DK + 1) {
        pcl[b * NCH + chunk] = sm_red[0] + sm_red[1];
    }
    __syncthreads();   // all waves' stores complete (vmcnt) before the ticket
    if (tid == 0) {
        int old = __hip_atomic_fetch_add(&cnt[b], 1, __ATOMIC_ACQ_REL, __HIP_MEMORY_SCOPE_AGENT);
        sm_done = (old == NCH - 1) ? 1 : 0;
    }
    __syncthreads();

    // --- last block for this b: reduce partials, write text, next LSTM ---
    if (sm_done) {
        __shared__ float sm_s[DK];
        __shared__ float sm_S;
        float r = 0.f;
        if (tid < DK) {
            #pragma unroll
            for (int k = 0; k < NCH; ++k)
                r += agent_load(&pctx[((size_t)b * NCH + k) * DK + tid]);
        } else if (tid == DK) {
            float s = 0.f;
            #pragma unroll
            for (int k = 0; k < NCH; ++k) s += agent_load(&psum[b * NCH + k]);
            sm_S = s;
        } else if (tid == DK + 1 && t > 0) {
            float clv = 0.f;
            #pragma unroll
            for (int k = 0; k < NCH; ++k) clv += agent_load(&pcl[b * NCH + k]);
            atomicAdd(out_closs, clv * (1.f / B));
        }
        __syncthreads();
        if (tid < DK) {
            float ct = r / sm_S;
            __builtin_nontemporal_store(ct, &out_text[((size_t)b * T + t) * DK + tid]);
            sm_s[tid] = ct;
        }
        if (tid == 0) {
            Sred[cur * B + b] = sm_S;
            cnt[b] = 0;
        }
        __syncthreads();
        lstm_phase(tid, b, sm_s, hst, cst, decq, W_ih, W_hh, b_ih, b_hh, W_x, b_attn);
    }
}

// ---- epilogue: last step's attention + closs term ------------------------
__global__ __launch_bounds__(256) void epilogue_kernel(
    const float* __restrict__ p, const float* __restrict__ cov, const float* __restrict__ Sred,
    float* __restrict__ out_attn, float* out_closs, int T)
{
    const int tid = threadIdx.x;
    const int b = blockIdx.x & (B - 1);
    const int chunk = blockIdx.x >> 5;
    const int n = chunk * 256 + tid;
    const size_t bn = (size_t)b * NN + n;
    float invS = 1.f / Sred[((T - 1) & 1) * B + b];
    float ap = p[bn] * invS;
    __builtin_nontemporal_store(ap, &out_attn[((size_t)b * T + (T - 1)) * NN + n]);
    float cl = fminf(ap, cov[bn]);
    #pragma unroll
    for (int off = 32; off; off >>= 1) cl += __shfl_xor(cl, off, 64);
    __shared__ float sred[4];
    if ((tid & 63) == 0) sred[tid >> 6] = cl;
    __syncthreads();
    if (tid == 0)
        atomicAdd(out_closs, (sred[0] + sred[1] + sred[2] + sred[3]) * (1.f / B));
}

extern "C" void kernel_launch(void* const* d_in, const int* in_sizes, int n_in,
                              void* d_out, int out_size, void* d_ws, size_t ws_size,
                              hipStream_t stream) {
    const float* z      = (const float*)d_in[0];
    const float* mask   = (const float*)d_in[1];
    const float* h0     = (const float*)d_in[2];
    const float* c0     = (const float*)d_in[3];
    const float* W_ih   = (const float*)d_in[4];
    const float* W_hh   = (const float*)d_in[5];
    const float* b_ih   = (const float*)d_in[6];
    const float* b_hh   = (const float*)d_in[7];
    const float* W_x    = (const float*)d_in[8];
    const float* W_z    = (const float*)d_in[9];
    const float* w_c    = (const float*)d_in[10];
    const float* b_attn = (const float*)d_in[11];
    const float* v      = (const float*)d_in[12];

    int T = (out_size - 1) / (B * (NN + DK));
    if (T < 1) T = 1;

    float* ws   = (float*)d_ws;
    float* zf   = ws + OFF_ZF;
    float* p    = ws + OFF_P;
    float* cov  = ws + OFF_COV;
    float* Sr   = ws + OFF_SRED;
    float* pctx = ws + OFF_PCTX;
    float* psum = ws + OFF_PSUM;
    float* pcl  = ws + OFF_PCL;
    float* decq = ws + OFF_DECQ;
    float* hst  = ws + OFF_HST;
    float* cst  = ws + OFF_CST;
    int*   cnt  = (int*)(ws + OFF_CNT);

    float* out_text  = (float*)d_out;
    float* out_attn  = out_text + (size_t)B * T * DK;
    float* out_closs = out_attn + (size_t)B * T * NN;

    zfea_kernel<<<(B * NN) / 32, 256, 0, stream>>>(z, W_z, zf);
    prologue_kernel<<<B, 256, 0, stream>>>(h0, c0, cov, decq, hst, cst,
                                           cnt, out_closs,
                                           W_ih, W_hh, b_ih, b_hh, W_x, b_attn);
    for (int t = 0; t < T; ++t) {
        step_kernel<<<B * NCH, 512, 0, stream>>>(z, mask, w_c, v, zf, p, cov,
                                                 Sr, pctx, psum, pcl,
                                                 decq, hst, cst, cnt,
                                                 W_ih, W_hh, b_ih, b_hh, W_x, b_attn,
                                                 out_text, out_attn, out_closs, t, T);
    }
    epilogue_kernel<<<512, 256, 0, stream>>>(p, cov, Sr, out_attn, out_closs, T);
}

// Round 5
// 3698.945 us; speedup vs baseline: 4.2170x; 1.4131x over previous
//
#include <hip/hip_runtime.h>
#include <hip/hip_bf16.h>
#include <math.h>

#define B 32
#define NN 4096
#define DK 128
#define HH 128
#define AA 128
#define NCH 32        // chunks per batch row
#define CHN 128       // n per chunk

// ws layout (in floats)
static const size_t OFF_ZF   = 0;                         // B*NN*AA
static const size_t OFF_P    = OFF_ZF + (size_t)B*NN*AA;  // B*NN
static const size_t OFF_COV  = OFF_P + (size_t)B*NN;      // B*NN
static const size_t OFF_SRED = OFF_COV + (size_t)B*NN;    // 2*B
static const size_t OFF_PCTX = OFF_SRED + 2*B;            // B*NCH*DK
static const size_t OFF_PSUM = OFF_PCTX + (size_t)B*NCH*DK; // B*NCH
static const size_t OFF_PCL  = OFF_PSUM + (size_t)B*NCH;  // B*NCH
static const size_t OFF_DECQ = OFF_PCL + (size_t)B*NCH;   // B*AA
static const size_t OFF_HST  = OFF_DECQ + (size_t)B*AA;   // B*HH
static const size_t OFF_CST  = OFF_HST + (size_t)B*HH;    // B*HH
static const size_t OFF_CLA  = OFF_CST + (size_t)B*HH;    // B floats (closs accum)

__device__ __forceinline__ float fast_tanh(float x) {
    float e = __expf(2.f * x);
    return 1.f - 2.f / (e + 1.f);
}
__device__ __forceinline__ float fast_sig(float x) {
    return 1.f / (1.f + __expf(-x));
}

// ---- LSTM + dec_fea ----------------------------------------------------
// Workers are tid<256; every thread of the block must call (has barriers).
__device__ void lstm_phase(int tid, int b, const float* __restrict__ sm_s,
                           float* hst, float* cst, float* decq,
                           const float* __restrict__ W_ih, const float* __restrict__ W_hh,
                           const float* __restrict__ b_ih, const float* __restrict__ b_hh,
                           const float* __restrict__ W_x, const float* __restrict__ b_attn)
{
    __shared__ float sm_h[HH];
    __shared__ float sm_g[4 * HH];
    __shared__ float sm_x[2 * HH];
    if (tid < HH) sm_h[tid] = hst[b * HH + tid];
    __syncthreads();
    if (tid < 256) {
        int j0 = tid, j1 = tid + 256;
        float g0 = b_ih[j0] + b_hh[j0];
        float g1 = b_ih[j1] + b_hh[j1];
        const float4* wi0 = (const float4*)(W_ih + (size_t)j0 * DK);
        const float4* wh0 = (const float4*)(W_hh + (size_t)j0 * HH);
        const float4* wi1 = (const float4*)(W_ih + (size_t)j1 * DK);
        const float4* wh1 = (const float4*)(W_hh + (size_t)j1 * HH);
        #pragma unroll 8
        for (int d4 = 0; d4 < DK / 4; ++d4) {
            float4 s4 = ((const float4*)sm_s)[d4];
            float4 h4 = ((const float4*)sm_h)[d4];
            float4 a0 = wi0[d4], a1 = wi1[d4];
            float4 c0 = wh0[d4], c1 = wh1[d4];
            g0 += s4.x*a0.x + s4.y*a0.y + s4.z*a0.z + s4.w*a0.w
                + h4.x*c0.x + h4.y*c0.y + h4.z*c0.z + h4.w*c0.w;
            g1 += s4.x*a1.x + s4.y*a1.y + s4.z*a1.z + s4.w*a1.w
                + h4.x*c1.x + h4.y*c1.y + h4.z*c1.z + h4.w*c1.w;
        }
        sm_g[j0] = g0; sm_g[j1] = g1;
    }
    __syncthreads();
    if (tid < HH) {
        float ig = sm_g[tid], fg = sm_g[HH + tid];
        float gg = sm_g[2 * HH + tid], og = sm_g[3 * HH + tid];
        float cold = cst[b * HH + tid];
        float cn = fast_sig(fg) * cold + fast_sig(ig) * fast_tanh(gg);
        float hn = fast_sig(og) * fast_tanh(cn);
        cst[b * HH + tid] = cn;
        hst[b * HH + tid] = hn;
        sm_x[tid] = hn;
        sm_x[HH + tid] = cn;
    }
    __syncthreads();
    if (tid < AA) {
        float df = b_attn[tid];
        #pragma unroll 8
        for (int k4 = 0; k4 < (2 * HH) / 4; ++k4) {
            float4 xv = ((const float4*)sm_x)[k4];
            df += xv.x * W_x[(size_t)(4 * k4 + 0) * AA + tid]
                + xv.y * W_x[(size_t)(4 * k4 + 1) * AA + tid]
                + xv.z * W_x[(size_t)(4 * k4 + 2) * AA + tid]
                + xv.w * W_x[(size_t)(4 * k4 + 3) * AA + tid];
        }
        decq[b * AA + tid] = df;
    }
    __syncthreads();
}

// ---- z_fea = z @ W_z ----------------------------------------------------
__global__ __launch_bounds__(256) void zfea_kernel(const float* __restrict__ z,
                                                   const float* __restrict__ Wz,
                                                   float* __restrict__ zf)
{
    __shared__ float sz[32 * DK];  // 16 KB
    const int tid = threadIdx.x;
    const size_t r0 = (size_t)blockIdx.x * 32;
    const float4* zsrc = (const float4*)(z + r0 * DK);
    float4* sz4 = (float4*)sz;
    #pragma unroll
    for (int i = 0; i < 4; ++i) sz4[i * 256 + tid] = zsrc[i * 256 + tid];
    __syncthreads();

    const int a4 = tid & 31;   // cols 4*a4 .. 4*a4+3
    const int g  = tid >> 5;   // rows g*4 .. g*4+3
    float4 acc[4];
    #pragma unroll
    for (int r = 0; r < 4; ++r) acc[r] = make_float4(0.f, 0.f, 0.f, 0.f);
    const float4* Wz4 = (const float4*)Wz;  // [128 d][32 col-quads]
    for (int d4 = 0; d4 < 32; ++d4) {
        float4 w0 = Wz4[(4 * d4 + 0) * 32 + a4];
        float4 w1 = Wz4[(4 * d4 + 1) * 32 + a4];
        float4 w2 = Wz4[(4 * d4 + 2) * 32 + a4];
        float4 w3 = Wz4[(4 * d4 + 3) * 32 + a4];
        #pragma unroll
        for (int r = 0; r < 4; ++r) {
            float4 zv = *(const float4*)(&sz[(g * 4 + r) * DK + 4 * d4]);
            acc[r].x += zv.x * w0.x + zv.y * w1.x + zv.z * w2.x + zv.w * w3.x;
            acc[r].y += zv.x * w0.y + zv.y * w1.y + zv.z * w2.y + zv.w * w3.y;
            acc[r].z += zv.x * w0.z + zv.y * w1.z + zv.z * w2.z + zv.w * w3.z;
            acc[r].w += zv.x * w0.w + zv.y * w1.w + zv.z * w2.w + zv.w * w3.w;
        }
    }
    #pragma unroll
    for (int r = 0; r < 4; ++r)
        *(float4*)(&zf[(r0 + g * 4 + r) * AA + 4 * a4]) = acc[r];
}

// ---- prologue ------------------------------------------------------------
__global__ __launch_bounds__(256) void prologue_kernel(
    const float* __restrict__ h0, const float* __restrict__ c0,
    float* cov, float* decq, float* hst, float* cst,
    float* cla, float* out_closs,
    const float* __restrict__ W_ih, const float* __restrict__ W_hh,
    const float* __restrict__ b_ih, const float* __restrict__ b_hh,
    const float* __restrict__ W_x, const float* __restrict__ b_attn)
{
    int b = blockIdx.x;
    int tid = threadIdx.x;
    float4 zero4 = make_float4(0.f, 0.f, 0.f, 0.f);
    float4* c4 = (float4*)(cov + (size_t)b * NN);
    for (int i = tid; i < NN / 4; i += 256) c4[i] = zero4;
    if (tid == 0) {
        cla[b] = 0.f;
        if (b == 0) *out_closs = 0.f;
    }
    if (tid < HH) {
        hst[b * HH + tid] = h0[b * HH + tid];
        cst[b * HH + tid] = c0[b * HH + tid];
    }
    __shared__ float sm_s[DK];
    if (tid < DK) sm_s[tid] = 0.f;
    __syncthreads();
    lstm_phase(tid, b, sm_s, hst, cst, decq, W_ih, W_hh, b_ih, b_hh, W_x, b_attn);
}

// ---- step part A: attention streaming (no atomics, no fences) ------------
// grid 1024 = 32 b * 32 chunks of 128 n; block 512 (8 waves, 16 n/wave).
__global__ __launch_bounds__(512, 8) void attn_kernel(
    const float* __restrict__ z, const float* __restrict__ mask,
    const float* __restrict__ w_c, const float* __restrict__ v,
    const float* __restrict__ zf, float* __restrict__ p, float* __restrict__ cov,
    const float* __restrict__ Sred, float* __restrict__ pctx,
    float* __restrict__ psum, float* __restrict__ pcl,
    const float* __restrict__ decq,
    float* __restrict__ out_attn,
    int t, int T)
{
    const int tid = threadIdx.x;
    const int b = blockIdx.x & (B - 1);
    const int chunk = blockIdx.x >> 5;
    const int n0 = chunk * CHN;
    const int prv = (t ^ 1) & 1;

    __shared__ float sm_cov[CHN];
    __shared__ float sm_mask[CHN];
    __shared__ float sm_p[CHN];
    __shared__ float sm_ctx[8][DK];
    __shared__ float sm_sump[8];
    __shared__ float sm_red[2];

    // --- B.1: finalize previous step's attention lazily; stage mask ---
    if (tid < CHN) {
        int n = n0 + tid;
        size_t bn = (size_t)b * NN + n;
        float covn = cov[bn];
        float closs_part = 0.f;
        if (t > 0) {
            float invS = 1.f / Sred[prv * B + b];
            float ap = p[bn] * invS;
            __builtin_nontemporal_store(ap, &out_attn[((size_t)b * T + (t - 1)) * NN + n]);
            closs_part = fminf(ap, covn);
            covn += ap;
            cov[bn] = covn;
        }
        sm_cov[tid] = covn;
        #pragma unroll
        for (int off = 32; off; off >>= 1) closs_part += __shfl_xor(closs_part, off, 64);
        if ((tid & 63) == 0) sm_red[tid >> 6] = closs_part;
    } else if (tid < 2 * CHN) {
        sm_mask[tid - CHN] = mask[(size_t)b * NN + n0 + (tid - CHN)];
    }
    __syncthreads();

    // --- B.2: scores + exp + unnormalized context, 8 n per wave-iteration ---
    const int w = tid >> 6, l = tid & 63;
    const float2* zf2 = (const float2*)(zf + ((size_t)b * NN + n0) * AA);
    const float2* z2  = (const float2*)(z  + ((size_t)b * NN + n0) * DK);
    const float2 q   = ((const float2*)(decq + b * AA))[l];   // dec_fea + b_attn
    const float2 wc2 = ((const float2*)w_c)[l];
    const float2 v2  = ((const float2*)v)[l];
    float accx = 0.f, accy = 0.f;
    float sump = 0.f;
    #pragma unroll 1
    for (int i0 = 0; i0 < 16; i0 += 8) {
        const int nb = w * 16 + i0;
        float2 a2[8], zr[8];
        #pragma unroll
        for (int g = 0; g < 8; ++g) a2[g] = zf2[(size_t)(nb + g) * 64 + l];
        #pragma unroll
        for (int g = 0; g < 8; ++g) zr[g] = z2[(size_t)(nb + g) * 64 + l];
        float el[8];
        #pragma unroll
        for (int g = 0; g < 8; ++g) {
            float cvn = sm_cov[nb + g];
            float x0 = fmaf(cvn, wc2.x, a2[g].x + q.x);
            float x1 = fmaf(cvn, wc2.y, a2[g].y + q.y);
            el[g] = fast_tanh(x0) * v2.x + fast_tanh(x1) * v2.y;
        }
        #pragma unroll
        for (int off = 32; off; off >>= 1) {
            #pragma unroll
            for (int g = 0; g < 8; ++g) el[g] += __shfl_xor(el[g], off, 64);
        }
        #pragma unroll
        for (int g = 0; g < 8; ++g) {
            float pe = (sm_mask[nb + g] > 0.f) ? __expf(el[g]) : 0.f;
            if (l == 0) sm_p[nb + g] = pe;
            accx = fmaf(pe, zr[g].x, accx);
            accy = fmaf(pe, zr[g].y, accy);
            sump += pe;
        }
    }
    sm_ctx[w][2 * l]     = accx;
    sm_ctx[w][2 * l + 1] = accy;
    if (l == 0) sm_sump[w] = sump;
    __syncthreads();

    // --- B.3: private partial stores; visibility via kernel boundary ---
    if (tid < CHN) p[(size_t)b * NN + n0 + tid] = sm_p[tid];
    if (tid < DK) {
        float r = 0.f;
        #pragma unroll
        for (int ww = 0; ww < 8; ++ww) r += sm_ctx[ww][tid];
        pctx[((size_t)b * NCH + chunk) * DK + tid] = r;
    } else if (tid == DK) {
        float s8 = 0.f;
        #pragma unroll
        for (int ww = 0; ww < 8; ++ww) s8 += sm_sump[ww];
        psum[b * NCH + chunk] = s8;
    } else if (tid == DK + 1) {
        pcl[b * NCH + chunk] = sm_red[0] + sm_red[1];
    }
}

// ---- step part B: reduce partials, write text, LSTM, dec_fea -------------
// grid 32 blocks (one per b) x 256 threads. Tiny kernel.
__global__ __launch_bounds__(256) void finish_kernel(
    const float* __restrict__ pctx, const float* __restrict__ psum,
    const float* __restrict__ pcl,
    float* __restrict__ Sred, float* __restrict__ cla,
    float* __restrict__ out_text,
    float* hst, float* cst, float* decq,
    const float* __restrict__ W_ih, const float* __restrict__ W_hh,
    const float* __restrict__ b_ih, const float* __restrict__ b_hh,
    const float* __restrict__ W_x, const float* __restrict__ b_attn,
    int t, int T)
{
    const int b = blockIdx.x;
    const int tid = threadIdx.x;
    const int cur = t & 1;
    __shared__ float sm_s[DK];
    __shared__ float sm_S;

    float r = 0.f;
    if (tid < DK) {
        #pragma unroll
        for (int k = 0; k < NCH; ++k)
            r += pctx[((size_t)b * NCH + k) * DK + tid];
    } else if (tid == DK) {
        float s = 0.f;
        #pragma unroll
        for (int k = 0; k < NCH; ++k) s += psum[b * NCH + k];
        sm_S = s;
        Sred[cur * B + b] = s;
    } else if (tid == DK + 1) {
        float clv = 0.f;
        #pragma unroll
        for (int k = 0; k < NCH; ++k) clv += pcl[b * NCH + k];
        cla[b] += clv;   // single writer per b, no atomic needed
    }
    __syncthreads();
    if (tid < DK) {
        float ct = r / sm_S;
        __builtin_nontemporal_store(ct, &out_text[((size_t)b * T + t) * DK + tid]);
        sm_s[tid] = ct;
    }
    __syncthreads();
    lstm_phase(tid, b, sm_s, hst, cst, decq, W_ih, W_hh, b_ih, b_hh, W_x, b_attn);
}

// ---- epilogue: last step's attention + closs total -----------------------
__global__ __launch_bounds__(256) void epilogue_kernel(
    const float* __restrict__ p, const float* __restrict__ cov, const float* __restrict__ Sred,
    const float* __restrict__ cla,
    float* __restrict__ out_attn, float* out_closs, int T)
{
    const int tid = threadIdx.x;
    const int b = blockIdx.x & (B - 1);
    const int chunk = blockIdx.x >> 5;
    const int n = chunk * 256 + tid;
    const size_t bn = (size_t)b * NN + n;
    float invS = 1.f / Sred[((T - 1) & 1) * B + b];
    float ap = p[bn] * invS;
    __builtin_nontemporal_store(ap, &out_attn[((size_t)b * T + (T - 1)) * NN + n]);
    float cl = fminf(ap, cov[bn]);
    #pragma unroll
    for (int off = 32; off; off >>= 1) cl += __shfl_xor(cl, off, 64);
    __shared__ float sred[4];
    if ((tid & 63) == 0) sred[tid >> 6] = cl;
    __syncthreads();
    if (tid == 0) {
        float blocksum = (sred[0] + sred[1] + sred[2] + sred[3]);
        if (chunk == 0) blocksum += cla[b];   // per-b accumulated closs (steps 0..T-2)
        atomicAdd(out_closs, blocksum * (1.f / B));
    }
}

extern "C" void kernel_launch(void* const* d_in, const int* in_sizes, int n_in,
                              void* d_out, int out_size, void* d_ws, size_t ws_size,
                              hipStream_t stream) {
    const float* z      = (const float*)d_in[0];
    const float* mask   = (const float*)d_in[1];
    const float* h0     = (const float*)d_in[2];
    const float* c0     = (const float*)d_in[3];
    const float* W_ih   = (const float*)d_in[4];
    const float* W_hh   = (const float*)d_in[5];
    const float* b_ih   = (const float*)d_in[6];
    const float* b_hh   = (const float*)d_in[7];
    const float* W_x    = (const float*)d_in[8];
    const float* W_z    = (const float*)d_in[9];
    const float* w_c    = (const float*)d_in[10];
    const float* b_attn = (const float*)d_in[11];
    const float* v      = (const float*)d_in[12];

    int T = (out_size - 1) / (B * (NN + DK));
    if (T < 1) T = 1;

    float* ws   = (float*)d_ws;
    float* zf   = ws + OFF_ZF;
    float* p    = ws + OFF_P;
    float* cov  = ws + OFF_COV;
    float* Sr   = ws + OFF_SRED;
    float* pctx = ws + OFF_PCTX;
    float* psum = ws + OFF_PSUM;
    float* pcl  = ws + OFF_PCL;
    float* decq = ws + OFF_DECQ;
    float* hst  = ws + OFF_HST;
    float* cst  = ws + OFF_CST;
    float* cla  = ws + OFF_CLA;

    float* out_text  = (float*)d_out;
    float* out_attn  = out_text + (size_t)B * T * DK;
    float* out_closs = out_attn + (size_t)B * T * NN;

    zfea_kernel<<<(B * NN) / 32, 256, 0, stream>>>(z, W_z, zf);
    prologue_kernel<<<B, 256, 0, stream>>>(h0, c0, cov, decq, hst, cst,
                                           cla, out_closs,
                                           W_ih, W_hh, b_ih, b_hh, W_x, b_attn);
    for (int t = 0; t < T; ++t) {
        attn_kernel<<<B * NCH, 512, 0, stream>>>(z, mask, w_c, v, zf, p, cov,
                                                 Sr, pctx, psum, pcl, decq,
                                                 out_attn, t, T);
        finish_kernel<<<B, 256, 0, stream>>>(pctx, psum, pcl, Sr, cla, out_text,
                                             hst, cst, decq,
                                             W_ih, W_hh, b_ih, b_hh, W_x, b_attn,
                                             t, T);
    }
    epilogue_kernel<<<512, 256, 0, stream>>>(p, cov, Sr, cla, out_attn, out_closs, T);
}

// Round 7
// 2965.272 us; speedup vs baseline: 5.2604x; 1.2474x over previous
//
#include <hip/hip_runtime.h>
#include <hip/hip_bf16.h>
#include <hip/hip_fp16.h>
#include <math.h>

#define B 32
#define NN 4096
#define DK 128
#define HH 128
#define AA 128
#define NCH 32        // chunks per batch row
#define CHN 128       // n per chunk

// ws layout (in floats)
static const size_t OFF_ZF   = 0;                         // B*NN*AA/2 floats (fp16 zf)
static const size_t OFF_P    = OFF_ZF + (size_t)B*NN*AA/2; // B*NN
static const size_t OFF_COV  = OFF_P + (size_t)B*NN;      // B*NN
static const size_t OFF_SRED = OFF_COV + (size_t)B*NN;    // 2*B
static const size_t OFF_PCTX = OFF_SRED + 2*B;            // B*NCH*DK
static const size_t OFF_PSUM = OFF_PCTX + (size_t)B*NCH*DK; // B*NCH
static const size_t OFF_PCL  = OFF_PSUM + (size_t)B*NCH;  // B*NCH
static const size_t OFF_DECQ = OFF_PCL + (size_t)B*NCH;   // B*AA
static const size_t OFF_HST  = OFF_DECQ + (size_t)B*AA;   // B*HH
static const size_t OFF_CST  = OFF_HST + (size_t)B*HH;    // B*HH
static const size_t OFF_CLA  = OFF_CST + (size_t)B*HH;    // B floats (closs accum)

__device__ __forceinline__ float fast_tanh(float x) {
    float e = __expf(2.f * x);
    return 1.f - 2.f / (e + 1.f);
}
__device__ __forceinline__ float fast_sig(float x) {
    return 1.f / (1.f + __expf(-x));
}

// ---- LSTM + dec_fea ----------------------------------------------------
// Workers are tid<256; every thread of the block must call (has barriers).
__device__ void lstm_phase(int tid, int b, const float* __restrict__ sm_s,
                           float* hst, float* cst, float* decq,
                           const float* __restrict__ W_ih, const float* __restrict__ W_hh,
                           const float* __restrict__ b_ih, const float* __restrict__ b_hh,
                           const float* __restrict__ W_x, const float* __restrict__ b_attn)
{
    __shared__ float sm_h[HH];
    __shared__ float sm_g[4 * HH];
    __shared__ float sm_x[2 * HH];
    if (tid < HH) sm_h[tid] = hst[b * HH + tid];
    __syncthreads();
    if (tid < 256) {
        int j0 = tid, j1 = tid + 256;
        float g0 = b_ih[j0] + b_hh[j0];
        float g1 = b_ih[j1] + b_hh[j1];
        const float4* wi0 = (const float4*)(W_ih + (size_t)j0 * DK);
        const float4* wh0 = (const float4*)(W_hh + (size_t)j0 * HH);
        const float4* wi1 = (const float4*)(W_ih + (size_t)j1 * DK);
        const float4* wh1 = (const float4*)(W_hh + (size_t)j1 * HH);
        #pragma unroll 8
        for (int d4 = 0; d4 < DK / 4; ++d4) {
            float4 s4 = ((const float4*)sm_s)[d4];
            float4 h4 = ((const float4*)sm_h)[d4];
            float4 a0 = wi0[d4], a1 = wi1[d4];
            float4 c0 = wh0[d4], c1 = wh1[d4];
            g0 += s4.x*a0.x + s4.y*a0.y + s4.z*a0.z + s4.w*a0.w
                + h4.x*c0.x + h4.y*c0.y + h4.z*c0.z + h4.w*c0.w;
            g1 += s4.x*a1.x + s4.y*a1.y + s4.z*a1.z + s4.w*a1.w
                + h4.x*c1.x + h4.y*c1.y + h4.z*c1.z + h4.w*c1.w;
        }
        sm_g[j0] = g0; sm_g[j1] = g1;
    }
    __syncthreads();
    if (tid < HH) {
        float ig = sm_g[tid], fg = sm_g[HH + tid];
        float gg = sm_g[2 * HH + tid], og = sm_g[3 * HH + tid];
        float cold = cst[b * HH + tid];
        float cn = fast_sig(fg) * cold + fast_sig(ig) * fast_tanh(gg);
        float hn = fast_sig(og) * fast_tanh(cn);
        cst[b * HH + tid] = cn;
        hst[b * HH + tid] = hn;
        sm_x[tid] = hn;
        sm_x[HH + tid] = cn;
    }
    __syncthreads();
    if (tid < AA) {
        float df = b_attn[tid];
        #pragma unroll 8
        for (int k4 = 0; k4 < (2 * HH) / 4; ++k4) {
            float4 xv = ((const float4*)sm_x)[k4];
            df += xv.x * W_x[(size_t)(4 * k4 + 0) * AA + tid]
                + xv.y * W_x[(size_t)(4 * k4 + 1) * AA + tid]
                + xv.z * W_x[(size_t)(4 * k4 + 2) * AA + tid]
                + xv.w * W_x[(size_t)(4 * k4 + 3) * AA + tid];
        }
        decq[b * AA + tid] = df;
    }
    __syncthreads();
}

// ---- z_fea = z @ W_z  (stores fp16) -------------------------------------
__global__ __launch_bounds__(256) void zfea_kernel(const float* __restrict__ z,
                                                   const float* __restrict__ Wz,
                                                   __half* __restrict__ zfh)
{
    __shared__ float sz[32 * DK];  // 16 KB
    const int tid = threadIdx.x;
    const size_t r0 = (size_t)blockIdx.x * 32;
    const float4* zsrc = (const float4*)(z + r0 * DK);
    float4* sz4 = (float4*)sz;
    #pragma unroll
    for (int i = 0; i < 4; ++i) sz4[i * 256 + tid] = zsrc[i * 256 + tid];
    __syncthreads();

    const int a4 = tid & 31;   // cols 4*a4 .. 4*a4+3
    const int g  = tid >> 5;   // rows g*4 .. g*4+3
    float4 acc[4];
    #pragma unroll
    for (int r = 0; r < 4; ++r) acc[r] = make_float4(0.f, 0.f, 0.f, 0.f);
    const float4* Wz4 = (const float4*)Wz;  // [128 d][32 col-quads]
    for (int d4 = 0; d4 < 32; ++d4) {
        float4 w0 = Wz4[(4 * d4 + 0) * 32 + a4];
        float4 w1 = Wz4[(4 * d4 + 1) * 32 + a4];
        float4 w2 = Wz4[(4 * d4 + 2) * 32 + a4];
        float4 w3 = Wz4[(4 * d4 + 3) * 32 + a4];
        #pragma unroll
        for (int r = 0; r < 4; ++r) {
            float4 zv = *(const float4*)(&sz[(g * 4 + r) * DK + 4 * d4]);
            acc[r].x += zv.x * w0.x + zv.y * w1.x + zv.z * w2.x + zv.w * w3.x;
            acc[r].y += zv.x * w0.y + zv.y * w1.y + zv.z * w2.y + zv.w * w3.y;
            acc[r].z += zv.x * w0.z + zv.y * w1.z + zv.z * w2.z + zv.w * w3.z;
            acc[r].w += zv.x * w0.w + zv.y * w1.w + zv.z * w2.w + zv.w * w3.w;
        }
    }
    #pragma unroll
    for (int r = 0; r < 4; ++r) {
        __half2 h0 = __floats2half2_rn(acc[r].x, acc[r].y);
        __half2 h1 = __floats2half2_rn(acc[r].z, acc[r].w);
        __half2* dst = (__half2*)(zfh + (r0 + g * 4 + r) * AA + 4 * a4);
        dst[0] = h0;
        dst[1] = h1;
    }
}

// ---- prologue ------------------------------------------------------------
__global__ __launch_bounds__(256) void prologue_kernel(
    const float* __restrict__ h0, const float* __restrict__ c0,
    float* cov, float* decq, float* hst, float* cst,
    float* cla, float* out_closs,
    const float* __restrict__ W_ih, const float* __restrict__ W_hh,
    const float* __restrict__ b_ih, const float* __restrict__ b_hh,
    const float* __restrict__ W_x, const float* __restrict__ b_attn)
{
    int b = blockIdx.x;
    int tid = threadIdx.x;
    float4 zero4 = make_float4(0.f, 0.f, 0.f, 0.f);
    float4* c4 = (float4*)(cov + (size_t)b * NN);
    for (int i = tid; i < NN / 4; i += 256) c4[i] = zero4;
    if (tid == 0) {
        cla[b] = 0.f;
        if (b == 0) *out_closs = 0.f;
    }
    if (tid < HH) {
        hst[b * HH + tid] = h0[b * HH + tid];
        cst[b * HH + tid] = c0[b * HH + tid];
    }
    __shared__ float sm_s[DK];
    if (tid < DK) sm_s[tid] = 0.f;
    __syncthreads();
    lstm_phase(tid, b, sm_s, hst, cst, decq, W_ih, W_hh, b_ih, b_hh, W_x, b_attn);
}

// ---- step part A: attention streaming (no atomics, no fences) ------------
// grid 1024 = 32 b * 32 chunks of 128 n; block 512 (8 waves, 16 n/wave).
// Phase 1: all scores (fp16 zf, 32-lane groups, batched loads) -> sm_p.
// Phase 2: context accumulation (fp32 z, p known, pure streaming).
__global__ __launch_bounds__(512, 8) void attn_kernel(
    const float* __restrict__ z, const float* __restrict__ mask,
    const float* __restrict__ w_c, const float* __restrict__ v,
    const __half* __restrict__ zfh, float* __restrict__ p, float* __restrict__ cov,
    const float* __restrict__ Sred, float* __restrict__ pctx,
    float* __restrict__ psum, float* __restrict__ pcl,
    const float* __restrict__ decq,
    float* __restrict__ out_attn,
    int t, int T)
{
    const int tid = threadIdx.x;
    const int b = blockIdx.x & (B - 1);
    const int chunk = blockIdx.x >> 5;
    const int n0 = chunk * CHN;
    const int prv = (t ^ 1) & 1;

    __shared__ float sm_cov[CHN];
    __shared__ float sm_mask[CHN];
    __shared__ float sm_p[CHN];
    __shared__ float sm_ctx[8][DK];
    __shared__ float sm_sump[8];
    __shared__ float sm_red[2];

    // --- B.1: finalize previous step's attention lazily; stage mask ---
    if (tid < CHN) {
        int n = n0 + tid;
        size_t bn = (size_t)b * NN + n;
        float covn = cov[bn];
        float closs_part = 0.f;
        if (t > 0) {
            float invS = 1.f / Sred[prv * B + b];
            float ap = p[bn] * invS;
            __builtin_nontemporal_store(ap, &out_attn[((size_t)b * T + (t - 1)) * NN + n]);
            closs_part = fminf(ap, covn);
            covn += ap;
            cov[bn] = covn;
        }
        sm_cov[tid] = covn;
        #pragma unroll
        for (int off = 32; off; off >>= 1) closs_part += __shfl_xor(closs_part, off, 64);
        if ((tid & 63) == 0) sm_red[tid >> 6] = closs_part;
    } else if (tid < 2 * CHN) {
        sm_mask[tid - CHN] = mask[(size_t)b * NN + n0 + (tid - CHN)];
    }
    __syncthreads();

    // --- Phase 1: scores. wave w owns n in [w*16, w*16+16).
    // 32-lane group g2 = l>>5 handles n = w*16 + 2*it + g2; lane32 owns 4 features.
    const int w = tid >> 6, l = tid & 63;
    const int g2 = l >> 5, lane32 = l & 31;
    const float4 q4  = *(const float4*)(decq + b * AA + 4 * lane32);
    const float4 wc4 = *(const float4*)(w_c + 4 * lane32);
    const float4 v4  = *(const float4*)(v + 4 * lane32);

    float2 raw[8];
    {
        const char* zbase = (const char*)(zfh + ((size_t)b * NN + n0) * AA) + 8 * lane32;
        const int nbase = w * 16 + g2;
        #pragma unroll
        for (int it = 0; it < 8; ++it)
            raw[it] = *(const float2*)(zbase + (size_t)(nbase + 2 * it) * (AA * 2));
    }
    float sump = 0.f;
    float el[8];
    #pragma unroll
    for (int it = 0; it < 8; ++it) {
        const int nl = w * 16 + 2 * it + g2;
        const float cvn = sm_cov[nl];
        __half2 ha = *(__half2*)&raw[it].x;
        __half2 hb = *(__half2*)&raw[it].y;
        float2 fa = __half22float2(ha);
        float2 fb = __half22float2(hb);
        float x0 = fmaf(cvn, wc4.x, fa.x + q4.x);
        float x1 = fmaf(cvn, wc4.y, fa.y + q4.y);
        float x2 = fmaf(cvn, wc4.z, fb.x + q4.z);
        float x3 = fmaf(cvn, wc4.w, fb.y + q4.w);
        el[it] = fast_tanh(x0) * v4.x + fast_tanh(x1) * v4.y
               + fast_tanh(x2) * v4.z + fast_tanh(x3) * v4.w;
    }
    #pragma unroll
    for (int off = 16; off; off >>= 1) {
        #pragma unroll
        for (int it = 0; it < 8; ++it) el[it] += __shfl_xor(el[it], off, 64);
    }
    #pragma unroll
    for (int it = 0; it < 8; ++it) {
        const int nl = w * 16 + 2 * it + g2;
        float pe = (sm_mask[nl] > 0.f) ? __expf(el[it]) : 0.f;
        if (lane32 == 0) sm_p[nl] = pe;
        sump += pe;
    }
    sump += __shfl_xor(sump, 32, 64);   // combine the two 32-groups
    if (l == 0) sm_sump[w] = sump;
    __syncthreads();

    // --- Phase 2: context accumulation; p known, pure streaming ---
    const float2* z2 = (const float2*)(z + ((size_t)b * NN + n0) * DK);
    float accx = 0.f, accy = 0.f;
    #pragma unroll 1
    for (int bt = 0; bt < 2; ++bt) {
        const int nb = w * 16 + bt * 8;
        float2 zr[8];
        #pragma unroll
        for (int g = 0; g < 8; ++g) zr[g] = z2[(size_t)(nb + g) * 64 + l];
        #pragma unroll
        for (int g = 0; g < 8; ++g) {
            float pe = sm_p[nb + g];
            accx = fmaf(pe, zr[g].x, accx);
            accy = fmaf(pe, zr[g].y, accy);
        }
    }
    sm_ctx[w][2 * l]     = accx;
    sm_ctx[w][2 * l + 1] = accy;
    __syncthreads();

    // --- B.3: private partial stores; visibility via kernel boundary ---
    if (tid < CHN) p[(size_t)b * NN + n0 + tid] = sm_p[tid];
    if (tid < DK) {
        float r = 0.f;
        #pragma unroll
        for (int ww = 0; ww < 8; ++ww) r += sm_ctx[ww][tid];
        pctx[((size_t)b * NCH + chunk) * DK + tid] = r;
    } else if (tid == DK) {
        float s8 = 0.f;
        #pragma unroll
        for (int ww = 0; ww < 8; ++ww) s8 += sm_sump[ww];
        psum[b * NCH + chunk] = s8;
    } else if (tid == DK + 1) {
        pcl[b * NCH + chunk] = sm_red[0] + sm_red[1];
    }
}

// ---- step part B: reduce partials, write text, LSTM, dec_fea -------------
__global__ __launch_bounds__(256) void finish_kernel(
    const float* __restrict__ pctx, const float* __restrict__ psum,
    const float* __restrict__ pcl,
    float* __restrict__ Sred, float* __restrict__ cla,
    float* __restrict__ out_text,
    float* hst, float* cst, float* decq,
    const float* __restrict__ W_ih, const float* __restrict__ W_hh,
    const float* __restrict__ b_ih, const float* __restrict__ b_hh,
    const float* __restrict__ W_x, const float* __restrict__ b_attn,
    int t, int T)
{
    const int b = blockIdx.x;
    const int tid = threadIdx.x;
    const int cur = t & 1;
    __shared__ float sm_s[DK];
    __shared__ float sm_S;

    float r = 0.f;
    if (tid < DK) {
        #pragma unroll
        for (int k = 0; k < NCH; ++k)
            r += pctx[((size_t)b * NCH + k) * DK + tid];
    } else if (tid == DK) {
        float s = 0.f;
        #pragma unroll
        for (int k = 0; k < NCH; ++k) s += psum[b * NCH + k];
        sm_S = s;
        Sred[cur * B + b] = s;
    } else if (tid == DK + 1) {
        float clv = 0.f;
        #pragma unroll
        for (int k = 0; k < NCH; ++k) clv += pcl[b * NCH + k];
        cla[b] += clv;   // single writer per b, no atomic needed
    }
    __syncthreads();
    if (tid < DK) {
        float ct = r / sm_S;
        __builtin_nontemporal_store(ct, &out_text[((size_t)b * T + t) * DK + tid]);
        sm_s[tid] = ct;
    }
    __syncthreads();
    lstm_phase(tid, b, sm_s, hst, cst, decq, W_ih, W_hh, b_ih, b_hh, W_x, b_attn);
}

// ---- epilogue: last step's attention + closs total -----------------------
__global__ __launch_bounds__(256) void epilogue_kernel(
    const float* __restrict__ p, const float* __restrict__ cov, const float* __restrict__ Sred,
    const float* __restrict__ cla,
    float* __restrict__ out_attn, float* out_closs, int T)
{
    const int tid = threadIdx.x;
    const int b = blockIdx.x & (B - 1);
    const int chunk = blockIdx.x >> 5;
    const int n = chunk * 256 + tid;
    const size_t bn = (size_t)b * NN + n;
    float invS = 1.f / Sred[((T - 1) & 1) * B + b];
    float ap = p[bn] * invS;
    __builtin_nontemporal_store(ap, &out_attn[((size_t)b * T + (T - 1)) * NN + n]);
    float cl = fminf(ap, cov[bn]);
    #pragma unroll
    for (int off = 32; off; off >>= 1) cl += __shfl_xor(cl, off, 64);
    __shared__ float sred[4];
    if ((tid & 63) == 0) sred[tid >> 6] = cl;
    __syncthreads();
    if (tid == 0) {
        float blocksum = (sred[0] + sred[1] + sred[2] + sred[3]);
        if (chunk == 0) blocksum += cla[b];   // per-b accumulated closs (steps 0..T-2)
        atomicAdd(out_closs, blocksum * (1.f / B));
    }
}

extern "C" void kernel_launch(void* const* d_in, const int* in_sizes, int n_in,
                              void* d_out, int out_size, void* d_ws, size_t ws_size,
                              hipStream_t stream) {
    const float* z      = (const float*)d_in[0];
    const float* mask   = (const float*)d_in[1];
    const float* h0     = (const float*)d_in[2];
    const float* c0     = (const float*)d_in[3];
    const float* W_ih   = (const float*)d_in[4];
    const float* W_hh   = (const float*)d_in[5];
    const float* b_ih   = (const float*)d_in[6];
    const float* b_hh   = (const float*)d_in[7];
    const float* W_x    = (const float*)d_in[8];
    const float* W_z    = (const float*)d_in[9];
    const float* w_c    = (const float*)d_in[10];
    const float* b_attn = (const float*)d_in[11];
    const float* v      = (const float*)d_in[12];

    int T = (out_size - 1) / (B * (NN + DK));
    if (T < 1) T = 1;

    float* ws   = (float*)d_ws;
    __half* zfh = (__half*)(ws + OFF_ZF);
    float* p    = ws + OFF_P;
    float* cov  = ws + OFF_COV;
    float* Sr   = ws + OFF_SRED;
    float* pctx = ws + OFF_PCTX;
    float* psum = ws + OFF_PSUM;
    float* pcl  = ws + OFF_PCL;
    float* decq = ws + OFF_DECQ;
    float* hst  = ws + OFF_HST;
    float* cst  = ws + OFF_CST;
    float* cla  = ws + OFF_CLA;

    float* out_text  = (float*)d_out;
    float* out_attn  = out_text + (size_t)B * T * DK;
    float* out_closs = out_attn + (size_t)B * T * NN;

    zfea_kernel<<<(B * NN) / 32, 256, 0, stream>>>(z, W_z, zfh);
    prologue_kernel<<<B, 256, 0, stream>>>(h0, c0, cov, decq, hst, cst,
                                           cla, out_closs,
                                           W_ih, W_hh, b_ih, b_hh, W_x, b_attn);
    for (int t = 0; t < T; ++t) {
        attn_kernel<<<B * NCH, 512, 0, stream>>>(z, mask, w_c, v, zfh, p, cov,
                                                 Sr, pctx, psum, pcl, decq,
                                                 out_attn, t, T);
        finish_kernel<<<B, 256, 0, stream>>>(pctx, psum, pcl, Sr, cla, out_text,
                                             hst, cst, decq,
                                             W_ih, W_hh, b_ih, b_hh, W_x, b_attn,
                                             t, T);
    }
    epilogue_kernel<<<512, 256, 0, stream>>>(p, cov, Sr, cla, out_attn, out_closs, T);
}

// Round 8
// 2780.103 us; speedup vs baseline: 5.6107x; 1.0666x over previous
//
#include <hip/hip_runtime.h>
#include <hip/hip_bf16.h>
#include <hip/hip_fp16.h>
#include <math.h>

#define B 32
#define NN 4096
#define DK 128
#define HH 128
#define AA 128
#define NCH 32        // chunks per batch row
#define CHN 128       // n per chunk

// ws layout (in floats)
static const size_t OFF_ZF   = 0;                          // B*NN*AA/2 floats (fp16 zf)
static const size_t OFF_ZH   = OFF_ZF + (size_t)B*NN*AA/2; // B*NN*DK/2 floats (fp16 z)
static const size_t OFF_P    = OFF_ZH + (size_t)B*NN*DK/2; // B*NN
static const size_t OFF_COV  = OFF_P + (size_t)B*NN;       // B*NN
static const size_t OFF_SRED = OFF_COV + (size_t)B*NN;     // 2*B
static const size_t OFF_PCTX = OFF_SRED + 2*B;             // B*NCH*DK
static const size_t OFF_PSUM = OFF_PCTX + (size_t)B*NCH*DK; // B*NCH
static const size_t OFF_PCL  = OFF_PSUM + (size_t)B*NCH;   // B*NCH
static const size_t OFF_DECQ = OFF_PCL + (size_t)B*NCH;    // B*AA
static const size_t OFF_HST  = OFF_DECQ + (size_t)B*AA;    // B*HH
static const size_t OFF_CST  = OFF_HST + (size_t)B*HH;     // B*HH
static const size_t OFF_CLA  = OFF_CST + (size_t)B*HH;     // B floats (closs accum)

__device__ __forceinline__ float fast_tanh(float x) {
    float e = __expf(2.f * x);
    return 1.f - 2.f / (e + 1.f);
}
__device__ __forceinline__ float fast_sig(float x) {
    return 1.f / (1.f + __expf(-x));
}

// ---- LSTM + dec_fea ----------------------------------------------------
// Workers are tid<256; every thread of the block must call (has barriers).
__device__ void lstm_phase(int tid, int b, const float* __restrict__ sm_s,
                           float* hst, float* cst, float* decq,
                           const float* __restrict__ W_ih, const float* __restrict__ W_hh,
                           const float* __restrict__ b_ih, const float* __restrict__ b_hh,
                           const float* __restrict__ W_x, const float* __restrict__ b_attn)
{
    __shared__ float sm_h[HH];
    __shared__ float sm_g[4 * HH];
    __shared__ float sm_x[2 * HH];
    if (tid < HH) sm_h[tid] = hst[b * HH + tid];
    __syncthreads();
    if (tid < 256) {
        int j0 = tid, j1 = tid + 256;
        float g0 = b_ih[j0] + b_hh[j0];
        float g1 = b_ih[j1] + b_hh[j1];
        const float4* wi0 = (const float4*)(W_ih + (size_t)j0 * DK);
        const float4* wh0 = (const float4*)(W_hh + (size_t)j0 * HH);
        const float4* wi1 = (const float4*)(W_ih + (size_t)j1 * DK);
        const float4* wh1 = (const float4*)(W_hh + (size_t)j1 * HH);
        #pragma unroll 8
        for (int d4 = 0; d4 < DK / 4; ++d4) {
            float4 s4 = ((const float4*)sm_s)[d4];
            float4 h4 = ((const float4*)sm_h)[d4];
            float4 a0 = wi0[d4], a1 = wi1[d4];
            float4 c0 = wh0[d4], c1 = wh1[d4];
            g0 += s4.x*a0.x + s4.y*a0.y + s4.z*a0.z + s4.w*a0.w
                + h4.x*c0.x + h4.y*c0.y + h4.z*c0.z + h4.w*c0.w;
            g1 += s4.x*a1.x + s4.y*a1.y + s4.z*a1.z + s4.w*a1.w
                + h4.x*c1.x + h4.y*c1.y + h4.z*c1.z + h4.w*c1.w;
        }
        sm_g[j0] = g0; sm_g[j1] = g1;
    }
    __syncthreads();
    if (tid < HH) {
        float ig = sm_g[tid], fg = sm_g[HH + tid];
        float gg = sm_g[2 * HH + tid], og = sm_g[3 * HH + tid];
        float cold = cst[b * HH + tid];
        float cn = fast_sig(fg) * cold + fast_sig(ig) * fast_tanh(gg);
        float hn = fast_sig(og) * fast_tanh(cn);
        cst[b * HH + tid] = cn;
        hst[b * HH + tid] = hn;
        sm_x[tid] = hn;
        sm_x[HH + tid] = cn;
    }
    __syncthreads();
    if (tid < AA) {
        float df = b_attn[tid];
        #pragma unroll 8
        for (int k4 = 0; k4 < (2 * HH) / 4; ++k4) {
            float4 xv = ((const float4*)sm_x)[k4];
            df += xv.x * W_x[(size_t)(4 * k4 + 0) * AA + tid]
                + xv.y * W_x[(size_t)(4 * k4 + 1) * AA + tid]
                + xv.z * W_x[(size_t)(4 * k4 + 2) * AA + tid]
                + xv.w * W_x[(size_t)(4 * k4 + 3) * AA + tid];
        }
        decq[b * AA + tid] = df;
    }
    __syncthreads();
}

// ---- z_fea = z @ W_z (stores fp16) + z fp16 copy ------------------------
__global__ __launch_bounds__(256) void zfea_kernel(const float* __restrict__ z,
                                                   const float* __restrict__ Wz,
                                                   __half* __restrict__ zfh,
                                                   __half* __restrict__ zh)
{
    __shared__ float sz[32 * DK];  // 16 KB
    const int tid = threadIdx.x;
    const size_t r0 = (size_t)blockIdx.x * 32;
    const float4* zsrc = (const float4*)(z + r0 * DK);
    float4* sz4 = (float4*)sz;
    #pragma unroll
    for (int i = 0; i < 4; ++i) sz4[i * 256 + tid] = zsrc[i * 256 + tid];
    __syncthreads();

    // emit fp16 copy of z (coalesced)
    {
        __half2* zh2o = (__half2*)zh;
        #pragma unroll
        for (int k = 0; k < (32 * DK / 2) / 256; ++k) {
            int i = k * 256 + tid;
            __half2 hz = __floats2half2_rn(sz[2 * i], sz[2 * i + 1]);
            zh2o[r0 * (DK / 2) + i] = hz;
        }
    }

    const int a4 = tid & 31;   // cols 4*a4 .. 4*a4+3
    const int g  = tid >> 5;   // rows g*4 .. g*4+3
    float4 acc[4];
    #pragma unroll
    for (int r = 0; r < 4; ++r) acc[r] = make_float4(0.f, 0.f, 0.f, 0.f);
    const float4* Wz4 = (const float4*)Wz;  // [128 d][32 col-quads]
    for (int d4 = 0; d4 < 32; ++d4) {
        float4 w0 = Wz4[(4 * d4 + 0) * 32 + a4];
        float4 w1 = Wz4[(4 * d4 + 1) * 32 + a4];
        float4 w2 = Wz4[(4 * d4 + 2) * 32 + a4];
        float4 w3 = Wz4[(4 * d4 + 3) * 32 + a4];
        #pragma unroll
        for (int r = 0; r < 4; ++r) {
            float4 zv = *(const float4*)(&sz[(g * 4 + r) * DK + 4 * d4]);
            acc[r].x += zv.x * w0.x + zv.y * w1.x + zv.z * w2.x + zv.w * w3.x;
            acc[r].y += zv.x * w0.y + zv.y * w1.y + zv.z * w2.y + zv.w * w3.y;
            acc[r].z += zv.x * w0.z + zv.y * w1.z + zv.z * w2.z + zv.w * w3.z;
            acc[r].w += zv.x * w0.w + zv.y * w1.w + zv.z * w2.w + zv.w * w3.w;
        }
    }
    #pragma unroll
    for (int r = 0; r < 4; ++r) {
        __half2 h0 = __floats2half2_rn(acc[r].x, acc[r].y);
        __half2 h1 = __floats2half2_rn(acc[r].z, acc[r].w);
        __half2* dst = (__half2*)(zfh + (r0 + g * 4 + r) * AA + 4 * a4);
        dst[0] = h0;
        dst[1] = h1;
    }
}

// ---- prologue ------------------------------------------------------------
__global__ __launch_bounds__(256) void prologue_kernel(
    const float* __restrict__ h0, const float* __restrict__ c0,
    float* cov, float* decq, float* hst, float* cst,
    float* cla, float* out_closs,
    const float* __restrict__ W_ih, const float* __restrict__ W_hh,
    const float* __restrict__ b_ih, const float* __restrict__ b_hh,
    const float* __restrict__ W_x, const float* __restrict__ b_attn)
{
    int b = blockIdx.x;
    int tid = threadIdx.x;
    float4 zero4 = make_float4(0.f, 0.f, 0.f, 0.f);
    float4* c4 = (float4*)(cov + (size_t)b * NN);
    for (int i = tid; i < NN / 4; i += 256) c4[i] = zero4;
    if (tid == 0) {
        cla[b] = 0.f;
        if (b == 0) *out_closs = 0.f;
    }
    if (tid < HH) {
        hst[b * HH + tid] = h0[b * HH + tid];
        cst[b * HH + tid] = c0[b * HH + tid];
    }
    __shared__ float sm_s[DK];
    if (tid < DK) sm_s[tid] = 0.f;
    __syncthreads();
    lstm_phase(tid, b, sm_s, hst, cst, decq, W_ih, W_hh, b_ih, b_hh, W_x, b_attn);
}

// ---- step part A: attention streaming (no atomics, no fences) ------------
// grid 1024 = 32 b * 32 chunks of 128 n; block 512 (8 waves, 16 n/wave).
// Phase 1: all scores (fp16 zf) -> sm_p. Phase 2: context from fp16 z.
__global__ __launch_bounds__(512, 8) void attn_kernel(
    const __half* __restrict__ zh, const float* __restrict__ mask,
    const float* __restrict__ w_c, const float* __restrict__ v,
    const __half* __restrict__ zfh, float* __restrict__ p, float* __restrict__ cov,
    const float* __restrict__ Sred, float* __restrict__ pctx,
    float* __restrict__ psum, float* __restrict__ pcl,
    const float* __restrict__ decq,
    float* __restrict__ out_attn,
    int t, int T)
{
    const int tid = threadIdx.x;
    const int b = blockIdx.x & (B - 1);
    const int chunk = blockIdx.x >> 5;
    const int n0 = chunk * CHN;
    const int prv = (t ^ 1) & 1;

    __shared__ float sm_cov[CHN];
    __shared__ float sm_mask[CHN];
    __shared__ float sm_p[CHN];
    __shared__ float sm_ctx[8][DK];
    __shared__ float sm_sump[8];
    __shared__ float sm_red[2];

    // --- B.1: finalize previous step's attention lazily; stage mask ---
    if (tid < CHN) {
        int n = n0 + tid;
        size_t bn = (size_t)b * NN + n;
        float covn = cov[bn];
        float closs_part = 0.f;
        if (t > 0) {
            float invS = 1.f / Sred[prv * B + b];
            float ap = p[bn] * invS;
            __builtin_nontemporal_store(ap, &out_attn[((size_t)b * T + (t - 1)) * NN + n]);
            closs_part = fminf(ap, covn);
            covn += ap;
            cov[bn] = covn;
        }
        sm_cov[tid] = covn;
        #pragma unroll
        for (int off = 32; off; off >>= 1) closs_part += __shfl_xor(closs_part, off, 64);
        if ((tid & 63) == 0) sm_red[tid >> 6] = closs_part;
    } else if (tid < 2 * CHN) {
        sm_mask[tid - CHN] = mask[(size_t)b * NN + n0 + (tid - CHN)];
    }
    __syncthreads();

    // --- Phase 1: scores. wave w owns n in [w*16, w*16+16).
    // 32-lane group g2 = l>>5 handles n = w*16 + 2*it + g2; lane32 owns 4 features.
    const int w = tid >> 6, l = tid & 63;
    const int g2 = l >> 5, lane32 = l & 31;
    const float4 q4  = *(const float4*)(decq + b * AA + 4 * lane32);
    const float4 wc4 = *(const float4*)(w_c + 4 * lane32);
    const float4 v4  = *(const float4*)(v + 4 * lane32);

    float2 raw[8];
    {
        const char* zbase = (const char*)(zfh + ((size_t)b * NN + n0) * AA) + 8 * lane32;
        const int nbase = w * 16 + g2;
        #pragma unroll
        for (int it = 0; it < 8; ++it)
            raw[it] = *(const float2*)(zbase + (size_t)(nbase + 2 * it) * (AA * 2));
    }
    float sump = 0.f;
    float el[8];
    #pragma unroll
    for (int it = 0; it < 8; ++it) {
        const int nl = w * 16 + 2 * it + g2;
        const float cvn = sm_cov[nl];
        __half2 ha = *(__half2*)&raw[it].x;
        __half2 hb = *(__half2*)&raw[it].y;
        float2 fa = __half22float2(ha);
        float2 fb = __half22float2(hb);
        float x0 = fmaf(cvn, wc4.x, fa.x + q4.x);
        float x1 = fmaf(cvn, wc4.y, fa.y + q4.y);
        float x2 = fmaf(cvn, wc4.z, fb.x + q4.z);
        float x3 = fmaf(cvn, wc4.w, fb.y + q4.w);
        el[it] = fast_tanh(x0) * v4.x + fast_tanh(x1) * v4.y
               + fast_tanh(x2) * v4.z + fast_tanh(x3) * v4.w;
    }
    #pragma unroll
    for (int off = 16; off; off >>= 1) {
        #pragma unroll
        for (int it = 0; it < 8; ++it) el[it] += __shfl_xor(el[it], off, 64);
    }
    #pragma unroll
    for (int it = 0; it < 8; ++it) {
        const int nl = w * 16 + 2 * it + g2;
        float pe = (sm_mask[nl] > 0.f) ? __expf(el[it]) : 0.f;
        if (lane32 == 0) sm_p[nl] = pe;
        sump += pe;
    }
    sump += __shfl_xor(sump, 32, 64);   // combine the two 32-groups
    if (l == 0) sm_sump[w] = sump;
    __syncthreads();

    // --- Phase 2: context from fp16 z; lane owns d [4*lane32, 4*lane32+4) ---
    const uint2* zh2 = (const uint2*)(zh + ((size_t)b * NN + n0) * DK);
    float4 acc = make_float4(0.f, 0.f, 0.f, 0.f);
    #pragma unroll
    for (int it = 0; it < 8; ++it) {
        const int nl = w * 16 + 2 * it + g2;
        uint2 u = zh2[(size_t)nl * 32 + lane32];
        __half2 ha = *(__half2*)&u.x;
        __half2 hb = *(__half2*)&u.y;
        float2 fa = __half22float2(ha);
        float2 fb = __half22float2(hb);
        float pe = sm_p[nl];
        acc.x = fmaf(pe, fa.x, acc.x);
        acc.y = fmaf(pe, fa.y, acc.y);
        acc.z = fmaf(pe, fb.x, acc.z);
        acc.w = fmaf(pe, fb.y, acc.w);
    }
    // combine the two 32-groups (same d-range, different n)
    acc.x += __shfl_xor(acc.x, 32, 64);
    acc.y += __shfl_xor(acc.y, 32, 64);
    acc.z += __shfl_xor(acc.z, 32, 64);
    acc.w += __shfl_xor(acc.w, 32, 64);
    if (g2 == 0) *(float4*)(&sm_ctx[w][4 * lane32]) = acc;
    __syncthreads();

    // --- B.3: private partial stores; visibility via kernel boundary ---
    if (tid < CHN) p[(size_t)b * NN + n0 + tid] = sm_p[tid];
    if (tid < DK) {
        float r = 0.f;
        #pragma unroll
        for (int ww = 0; ww < 8; ++ww) r += sm_ctx[ww][tid];
        pctx[((size_t)b * NCH + chunk) * DK + tid] = r;
    } else if (tid == DK) {
        float s8 = 0.f;
        #pragma unroll
        for (int ww = 0; ww < 8; ++ww) s8 += sm_sump[ww];
        psum[b * NCH + chunk] = s8;
    } else if (tid == DK + 1) {
        pcl[b * NCH + chunk] = sm_red[0] + sm_red[1];
    }
}

// ---- step part B: reduce partials, write text, LSTM, dec_fea -------------
__global__ __launch_bounds__(256) void finish_kernel(
    const float* __restrict__ pctx, const float* __restrict__ psum,
    const float* __restrict__ pcl,
    float* __restrict__ Sred, float* __restrict__ cla,
    float* __restrict__ out_text,
    float* hst, float* cst, float* decq,
    const float* __restrict__ W_ih, const float* __restrict__ W_hh,
    const float* __restrict__ b_ih, const float* __restrict__ b_hh,
    const float* __restrict__ W_x, const float* __restrict__ b_attn,
    int t, int T)
{
    const int b = blockIdx.x;
    const int tid = threadIdx.x;
    const int cur = t & 1;
    __shared__ float sm_s[DK];
    __shared__ float sm_S;

    float r = 0.f;
    if (tid < DK) {
        #pragma unroll
        for (int k = 0; k < NCH; ++k)
            r += pctx[((size_t)b * NCH + k) * DK + tid];
    } else if (tid == DK) {
        float s = 0.f;
        #pragma unroll
        for (int k = 0; k < NCH; ++k) s += psum[b * NCH + k];
        sm_S = s;
        Sred[cur * B + b] = s;
    } else if (tid == DK + 1) {
        float clv = 0.f;
        #pragma unroll
        for (int k = 0; k < NCH; ++k) clv += pcl[b * NCH + k];
        cla[b] += clv;   // single writer per b, no atomic needed
    }
    __syncthreads();
    if (tid < DK) {
        float ct = r / sm_S;
        __builtin_nontemporal_store(ct, &out_text[((size_t)b * T + t) * DK + tid]);
        sm_s[tid] = ct;
    }
    __syncthreads();
    lstm_phase(tid, b, sm_s, hst, cst, decq, W_ih, W_hh, b_ih, b_hh, W_x, b_attn);
}

// ---- epilogue: last step's attention + closs total -----------------------
__global__ __launch_bounds__(256) void epilogue_kernel(
    const float* __restrict__ p, const float* __restrict__ cov, const float* __restrict__ Sred,
    const float* __restrict__ cla,
    float* __restrict__ out_attn, float* out_closs, int T)
{
    const int tid = threadIdx.x;
    const int b = blockIdx.x & (B - 1);
    const int chunk = blockIdx.x >> 5;
    const int n = chunk * 256 + tid;
    const size_t bn = (size_t)b * NN + n;
    float invS = 1.f / Sred[((T - 1) & 1) * B + b];
    float ap = p[bn] * invS;
    __builtin_nontemporal_store(ap, &out_attn[((size_t)b * T + (T - 1)) * NN + n]);
    float cl = fminf(ap, cov[bn]);
    #pragma unroll
    for (int off = 32; off; off >>= 1) cl += __shfl_xor(cl, off, 64);
    __shared__ float sred[4];
    if ((tid & 63) == 0) sred[tid >> 6] = cl;
    __syncthreads();
    if (tid == 0) {
        float blocksum = (sred[0] + sred[1] + sred[2] + sred[3]);
        if (chunk == 0) blocksum += cla[b];   // per-b accumulated closs (steps 0..T-2)
        atomicAdd(out_closs, blocksum * (1.f / B));
    }
}

extern "C" void kernel_launch(void* const* d_in, const int* in_sizes, int n_in,
                              void* d_out, int out_size, void* d_ws, size_t ws_size,
                              hipStream_t stream) {
    const float* z      = (const float*)d_in[0];
    const float* mask   = (const float*)d_in[1];
    const float* h0     = (const float*)d_in[2];
    const float* c0     = (const float*)d_in[3];
    const float* W_ih   = (const float*)d_in[4];
    const float* W_hh   = (const float*)d_in[5];
    const float* b_ih   = (const float*)d_in[6];
    const float* b_hh   = (const float*)d_in[7];
    const float* W_x    = (const float*)d_in[8];
    const float* W_z    = (const float*)d_in[9];
    const float* w_c    = (const float*)d_in[10];
    const float* b_attn = (const float*)d_in[11];
    const float* v      = (const float*)d_in[12];

    int T = (out_size - 1) / (B * (NN + DK));
    if (T < 1) T = 1;

    float* ws   = (float*)d_ws;
    __half* zfh = (__half*)(ws + OFF_ZF);
    __half* zh  = (__half*)(ws + OFF_ZH);
    float* p    = ws + OFF_P;
    float* cov  = ws + OFF_COV;
    float* Sr   = ws + OFF_SRED;
    float* pctx = ws + OFF_PCTX;
    float* psum = ws + OFF_PSUM;
    float* pcl  = ws + OFF_PCL;
    float* decq = ws + OFF_DECQ;
    float* hst  = ws + OFF_HST;
    float* cst  = ws + OFF_CST;
    float* cla  = ws + OFF_CLA;

    float* out_text  = (float*)d_out;
    float* out_attn  = out_text + (size_t)B * T * DK;
    float* out_closs = out_attn + (size_t)B * T * NN;

    zfea_kernel<<<(B * NN) / 32, 256, 0, stream>>>(z, W_z, zfh, zh);
    prologue_kernel<<<B, 256, 0, stream>>>(h0, c0, cov, decq, hst, cst,
                                           cla, out_closs,
                                           W_ih, W_hh, b_ih, b_hh, W_x, b_attn);
    for (int t = 0; t < T; ++t) {
        attn_kernel<<<B * NCH, 512, 0, stream>>>(zh, mask, w_c, v, zfh, p, cov,
                                                 Sr, pctx, psum, pcl, decq,
                                                 out_attn, t, T);
        finish_kernel<<<B, 256, 0, stream>>>(pctx, psum, pcl, Sr, cla, out_text,
                                             hst, cst, decq,
                                             W_ih, W_hh, b_ih, b_hh, W_x, b_attn,
                                             t, T);
    }
    epilogue_kernel<<<512, 256, 0, stream>>>(p, cov, Sr, cla, out_attn, out_closs, T);
}